// Round 1
// baseline (326.951 us; speedup 1.0000x reference)
//
#include <hip/hip_runtime.h>

// Problem shape (fixed by setup_inputs): B=2, C=4, D=128, H=192, W=192
#define NB 2
#define NC 4
#define NS (128 * 192 * 192)      // spatial voxels per batch = 4718592 (divisible by 4)
#define NTOT (NB * NS)            // 9437184
#define NQ (NTOT / 4)             // 2359296 float4-quads
#define NSQ (NS / 4)              // quads per batch
#define EPSF 1e-8f

// Workspace layout (ws is re-poisoned to 0xAA before every call -> k_init resets it)
struct Ws {
    unsigned int mn[8];   // float bits, index b*3 + (j-1), j in 1..3; z>=0 so uint order == float order
    unsigned int mx[8];
    double sum;           // offset 64, 8B aligned
};

__global__ void k_init(Ws* ws) {
    if (threadIdx.x < 6) {
        ws->mn[threadIdx.x] = 0x7F800000u;  // +inf
        ws->mx[threadIdx.x] = 0u;           // 0.0f (valid: z >= 0 always)
    }
    if (threadIdx.x == 0) ws->sum = 0.0;
}

// Pass 1: per-(b, class j>=1) spatial min/max of z = (target==j ? dist : 0)
__global__ void k_minmax(const int* __restrict__ tgt,
                         const float* __restrict__ dist,
                         Ws* __restrict__ ws) {
    float lmn[NB][3], lmx[NB][3];
#pragma unroll
    for (int b = 0; b < NB; b++)
#pragma unroll
        for (int j = 0; j < 3; j++) {
            lmn[b][j] = __int_as_float(0x7F800000);  // +inf
            lmx[b][j] = 0.f;
        }

    const int4* t4 = (const int4*)tgt;
    const float4* d4 = (const float4*)dist;
    const int stride = gridDim.x * blockDim.x;
    for (int q = blockIdx.x * blockDim.x + threadIdx.x; q < NQ; q += stride) {
        const int b = (q >= NSQ) ? 1 : 0;
        int4 t = t4[q];
        float4 d = d4[q];
        int tk[4] = {t.x, t.y, t.z, t.w};
        float dk[4] = {d.x, d.y, d.z, d.w};
#pragma unroll
        for (int k = 0; k < 4; k++) {
#pragma unroll
            for (int j = 0; j < 3; j++) {
                float z = (tk[k] == j + 1) ? dk[k] : 0.f;
                lmn[b][j] = fminf(lmn[b][j], z);
                lmx[b][j] = fmaxf(lmx[b][j], z);
            }
        }
    }

    // wave(64)-level butterfly, then cross-wave via LDS, then 12 atomics/block
#pragma unroll
    for (int b = 0; b < NB; b++)
#pragma unroll
        for (int j = 0; j < 3; j++) {
            float mn = lmn[b][j], mx = lmx[b][j];
            for (int off = 32; off; off >>= 1) {
                mn = fminf(mn, __shfl_down(mn, off, 64));
                mx = fmaxf(mx, __shfl_down(mx, off, 64));
            }
            lmn[b][j] = mn;
            lmx[b][j] = mx;
        }

    __shared__ float smn[4][6], smx[4][6];
    const int wid = threadIdx.x >> 6;
    const int lane = threadIdx.x & 63;
    if (lane == 0) {
#pragma unroll
        for (int b = 0; b < NB; b++)
#pragma unroll
            for (int j = 0; j < 3; j++) {
                smn[wid][b * 3 + j] = lmn[b][j];
                smx[wid][b * 3 + j] = lmx[b][j];
            }
    }
    __syncthreads();
    if (threadIdx.x < 6) {
        float mn = smn[0][threadIdx.x], mx = smx[0][threadIdx.x];
#pragma unroll
        for (int w = 1; w < 4; w++) {
            mn = fminf(mn, smn[w][threadIdx.x]);
            mx = fmaxf(mx, smx[w][threadIdx.x]);
        }
        atomicMin(&ws->mn[threadIdx.x], __float_as_uint(mn));
        atomicMax(&ws->mx[threadIdx.x], __float_as_uint(mx));
    }
}

// Pass 2: per-voxel  -sum_c dist_y_c * logsoftmax_c, summed into ws->sum
__global__ void k_loss(const float* __restrict__ x,
                       const int* __restrict__ tgt,
                       const float* __restrict__ dist,
                       Ws* __restrict__ ws) {
    float mnv[NB][3], scl[NB][3];
#pragma unroll
    for (int b = 0; b < NB; b++)
#pragma unroll
        for (int j = 0; j < 3; j++) {
            float mn = __uint_as_float(ws->mn[b * 3 + j]);
            float mx = __uint_as_float(ws->mx[b * 3 + j]);
            mnv[b][j] = mn;
            scl[b][j] = 1.0f / (mx + EPSF - mn);
        }

    const int4* t4 = (const int4*)tgt;
    const float4* d4 = (const float4*)dist;
    const float4* x4 = (const float4*)x;
    float lsum = 0.f;
    const int stride = gridDim.x * blockDim.x;
    for (int q = blockIdx.x * blockDim.x + threadIdx.x; q < NQ; q += stride) {
        const int b = (q >= NSQ) ? 1 : 0;
        const int s4 = q - b * NSQ;                       // quad index within batch
        const float4* xb = x4 + (size_t)b * NC * NSQ;
        float4 x0 = xb[s4];
        float4 x1 = xb[s4 + NSQ];
        float4 x2 = xb[s4 + 2 * NSQ];
        float4 x3 = xb[s4 + 3 * NSQ];
        int4 t = t4[q];
        float4 d = d4[q];
        int tk[4] = {t.x, t.y, t.z, t.w};
        float dk[4] = {d.x, d.y, d.z, d.w};
#pragma unroll
        for (int k = 0; k < 4; k++) {
            float a0 = ((const float*)&x0)[k];
            float a1 = ((const float*)&x1)[k];
            float a2 = ((const float*)&x2)[k];
            float a3 = ((const float*)&x3)[k];
            float m = fmaxf(fmaxf(a0, a1), fmaxf(a2, a3));
            float e = __expf(a0 - m) + __expf(a1 - m) + __expf(a2 - m) + __expf(a3 - m);
            float lse = m + __logf(e);
            int tt = tk[k];
            float w0 = (tt == 0) ? 1.f : 0.f;
            float z1 = (tt == 1) ? dk[k] : 0.f;
            float z2 = (tt == 2) ? dk[k] : 0.f;
            float z3 = (tt == 3) ? dk[k] : 0.f;
            float w1 = (z1 - mnv[b][0]) * scl[b][0];
            float w2 = (z2 - mnv[b][1]) * scl[b][1];
            float w3 = (z3 - mnv[b][2]) * scl[b][2];
            lsum += w0 * a0 + w1 * a1 + w2 * a2 + w3 * a3 - (w0 + w1 + w2 + w3) * lse;
        }
    }

    // block reduction -> one double atomic per block
    for (int off = 32; off; off >>= 1) lsum += __shfl_down(lsum, off, 64);
    __shared__ float ssum[4];
    if ((threadIdx.x & 63) == 0) ssum[threadIdx.x >> 6] = lsum;
    __syncthreads();
    if (threadIdx.x == 0) {
        double bs = (double)ssum[0] + (double)ssum[1] + (double)ssum[2] + (double)ssum[3];
        atomicAdd(&ws->sum, bs);
    }
}

__global__ void k_final(const Ws* __restrict__ ws, float* __restrict__ out) {
    if (threadIdx.x == 0 && blockIdx.x == 0)
        out[0] = (float)(-ws->sum / (double)NTOT);
}

extern "C" void kernel_launch(void* const* d_in, const int* in_sizes, int n_in,
                              void* d_out, int out_size, void* d_ws, size_t ws_size,
                              hipStream_t stream) {
    const float* net = (const float*)d_in[0];   // [B, C, D, H, W] fp32
    const int* tgt = (const int*)d_in[1];       // [B, 1, D, H, W] int
    const float* dist = (const float*)d_in[2];  // [B, D, H, W] fp32
    Ws* ws = (Ws*)d_ws;

    k_init<<<1, 64, 0, stream>>>(ws);
    k_minmax<<<2304, 256, 0, stream>>>(tgt, dist, ws);   // 4 quads/thread
    k_loss<<<4608, 256, 0, stream>>>(net, tgt, dist, ws); // 2 quads/thread
    k_final<<<1, 64, 0, stream>>>(ws, (float*)d_out);
}

// Round 2
// 321.755 us; speedup vs baseline: 1.0161x; 1.0161x over previous
//
#include <hip/hip_runtime.h>

// Problem shape (fixed by setup_inputs): B=2, C=4, D=128, H=192, W=192
#define NB 2
#define NC 4
#define NS (128 * 192 * 192)      // spatial voxels per batch = 4718592 (divisible by 4)
#define NTOT (NB * NS)            // 9437184
#define NSQ (NS / 4)              // float4-quads per batch = 1179648
#define EPSF 1e-8f
#define INF_BITS 0x7F800000u

// Workspace (re-poisoned to 0xAA before every call -> k_init resets it)
struct Ws {
    unsigned int mn[8];   // float bits, index b*3 + (j-1); z>=0 so uint order == float order
    unsigned int mx[8];
    double sum;           // 8B aligned at offset 64
};

__global__ void k_init(Ws* ws) {
    if (threadIdx.x < 6) {
        ws->mn[threadIdx.x] = INF_BITS;  // +inf
        ws->mx[threadIdx.x] = 0u;        // 0.0f (valid: z >= 0 always)
    }
    if (threadIdx.x == 0) ws->sum = 0.0;
}

// Pass 1: per-(b, class j>=1) spatial min/max of z = (target==j ? dist : 0).
// Batch index is BLOCK-UNIFORM (first half of grid -> b=0) so all per-class
// state lives in named scalar registers — no dynamically-indexed locals.
__global__ void k_minmax(const int* __restrict__ tgt,
                         const float* __restrict__ dist,
                         Ws* __restrict__ ws) {
    const int half = gridDim.x >> 1;
    const int b = (blockIdx.x >= half) ? 1 : 0;
    const int bid = blockIdx.x - b * half;
    const int stride = half * blockDim.x;

    const int4* t4 = (const int4*)tgt + (size_t)b * NSQ;
    const float4* d4 = (const float4*)dist + (size_t)b * NSQ;

    float mn1 = __uint_as_float(INF_BITS), mn2 = mn1, mn3 = mn1;
    float mx1 = 0.f, mx2 = 0.f, mx3 = 0.f;

    for (int q = bid * blockDim.x + threadIdx.x; q < NSQ; q += stride) {
        int4 t = t4[q];
        float4 d = d4[q];
        int tk[4] = {t.x, t.y, t.z, t.w};
        float dk[4] = {d.x, d.y, d.z, d.w};
#pragma unroll
        for (int k = 0; k < 4; k++) {
            float z1 = (tk[k] == 1) ? dk[k] : 0.f;
            float z2 = (tk[k] == 2) ? dk[k] : 0.f;
            float z3 = (tk[k] == 3) ? dk[k] : 0.f;
            mn1 = fminf(mn1, z1); mx1 = fmaxf(mx1, z1);
            mn2 = fminf(mn2, z2); mx2 = fmaxf(mx2, z2);
            mn3 = fminf(mn3, z3); mx3 = fmaxf(mx3, z3);
        }
    }

    // wave(64) butterfly
    for (int off = 32; off; off >>= 1) {
        mn1 = fminf(mn1, __shfl_down(mn1, off, 64));
        mn2 = fminf(mn2, __shfl_down(mn2, off, 64));
        mn3 = fminf(mn3, __shfl_down(mn3, off, 64));
        mx1 = fmaxf(mx1, __shfl_down(mx1, off, 64));
        mx2 = fmaxf(mx2, __shfl_down(mx2, off, 64));
        mx3 = fmaxf(mx3, __shfl_down(mx3, off, 64));
    }

    __shared__ float smn[4][3], smx[4][3];
    const int wid = threadIdx.x >> 6;
    if ((threadIdx.x & 63) == 0) {
        smn[wid][0] = mn1; smn[wid][1] = mn2; smn[wid][2] = mn3;
        smx[wid][0] = mx1; smx[wid][1] = mx2; smx[wid][2] = mx3;
    }
    __syncthreads();
    if (threadIdx.x < 3) {
        float mn = smn[0][threadIdx.x], mx = smx[0][threadIdx.x];
#pragma unroll
        for (int w = 1; w < 4; w++) {
            mn = fminf(mn, smn[w][threadIdx.x]);
            mx = fmaxf(mx, smx[w][threadIdx.x]);
        }
        atomicMin(&ws->mn[b * 3 + threadIdx.x], __float_as_uint(mn));
        atomicMax(&ws->mx[b * 3 + threadIdx.x], __float_as_uint(mx));
    }
}

// Pass 2: per-voxel  -sum_c dist_y_c * logsoftmax_c, summed into ws->sum.
// Batch index block-uniform; mn/scale live in 6 scalar registers.
__global__ void k_loss(const float* __restrict__ x,
                       const int* __restrict__ tgt,
                       const float* __restrict__ dist,
                       Ws* __restrict__ ws) {
    const int half = gridDim.x >> 1;
    const int b = (blockIdx.x >= half) ? 1 : 0;
    const int bid = blockIdx.x - b * half;
    const int stride = half * blockDim.x;

    const float mn1 = __uint_as_float(ws->mn[b * 3 + 0]);
    const float mn2 = __uint_as_float(ws->mn[b * 3 + 1]);
    const float mn3 = __uint_as_float(ws->mn[b * 3 + 2]);
    const float s1 = 1.0f / (__uint_as_float(ws->mx[b * 3 + 0]) + EPSF - mn1);
    const float s2 = 1.0f / (__uint_as_float(ws->mx[b * 3 + 1]) + EPSF - mn2);
    const float s3 = 1.0f / (__uint_as_float(ws->mx[b * 3 + 2]) + EPSF - mn3);

    const int4* t4 = (const int4*)tgt + (size_t)b * NSQ;
    const float4* d4 = (const float4*)dist + (size_t)b * NSQ;
    const float4* xb = (const float4*)x + (size_t)b * NC * NSQ;

    float lsum = 0.f;
    for (int q = bid * blockDim.x + threadIdx.x; q < NSQ; q += stride) {
        float4 x0 = xb[q];
        float4 x1 = xb[q + NSQ];
        float4 x2 = xb[q + 2 * NSQ];
        float4 x3 = xb[q + 3 * NSQ];
        int4 t = t4[q];
        float4 d = d4[q];
        int tk[4] = {t.x, t.y, t.z, t.w};
        float dk[4] = {d.x, d.y, d.z, d.w};
#pragma unroll
        for (int k = 0; k < 4; k++) {
            float a0 = ((const float*)&x0)[k];
            float a1 = ((const float*)&x1)[k];
            float a2 = ((const float*)&x2)[k];
            float a3 = ((const float*)&x3)[k];
            float m = fmaxf(fmaxf(a0, a1), fmaxf(a2, a3));
            float e = __expf(a0 - m) + __expf(a1 - m) + __expf(a2 - m) + __expf(a3 - m);
            float lse = m + __logf(e);
            int tt = tk[k];
            float w0 = (tt == 0) ? 1.f : 0.f;
            float z1 = (tt == 1) ? dk[k] : 0.f;
            float z2 = (tt == 2) ? dk[k] : 0.f;
            float z3 = (tt == 3) ? dk[k] : 0.f;
            float w1 = (z1 - mn1) * s1;
            float w2 = (z2 - mn2) * s2;
            float w3 = (z3 - mn3) * s3;
            lsum += w0 * a0 + w1 * a1 + w2 * a2 + w3 * a3 - (w0 + w1 + w2 + w3) * lse;
        }
    }

    // block reduction -> one double atomic per block
    for (int off = 32; off; off >>= 1) lsum += __shfl_down(lsum, off, 64);
    __shared__ float ssum[4];
    if ((threadIdx.x & 63) == 0) ssum[threadIdx.x >> 6] = lsum;
    __syncthreads();
    if (threadIdx.x == 0) {
        double bs = (double)ssum[0] + (double)ssum[1] + (double)ssum[2] + (double)ssum[3];
        atomicAdd(&ws->sum, bs);
    }
}

__global__ void k_final(const Ws* __restrict__ ws, float* __restrict__ out) {
    if (threadIdx.x == 0 && blockIdx.x == 0)
        out[0] = (float)(-ws->sum / (double)NTOT);
}

extern "C" void kernel_launch(void* const* d_in, const int* in_sizes, int n_in,
                              void* d_out, int out_size, void* d_ws, size_t ws_size,
                              hipStream_t stream) {
    const float* net = (const float*)d_in[0];   // [B, C, D, H, W] fp32
    const int* tgt = (const int*)d_in[1];       // [B, 1, D, H, W] int
    const float* dist = (const float*)d_in[2];  // [B, D, H, W] fp32
    Ws* ws = (Ws*)d_ws;

    k_init<<<1, 64, 0, stream>>>(ws);
    // 1152 blocks/batch x 256 thr = 294912 threads/batch -> exactly 4 iters over NSQ
    k_minmax<<<2304, 256, 0, stream>>>(tgt, dist, ws);
    // 2304 blocks/batch -> exactly 2 iters over NSQ
    k_loss<<<4608, 256, 0, stream>>>(net, tgt, dist, ws);
    k_final<<<1, 64, 0, stream>>>(ws, (float*)d_out);
}

// Round 3
// 280.626 us; speedup vs baseline: 1.1651x; 1.1466x over previous
//
#include <hip/hip_runtime.h>

// Problem shape (fixed by setup_inputs): B=2, C=4, D=128, H=192, W=192
#define NB 2
#define NC 4
#define NS (128 * 192 * 192)      // spatial voxels per batch = 4718592
#define NTOT (NB * NS)            // 9437184
#define NSQ (NS / 4)              // float4-quads per batch = 1179648
#define EPSF 1e-8f
#define INF_BITS 0x7F800000u

// Decomposition: loss = -(R0 + sum_{b,j} s_bj*(P_bj - mn_bj*Q_bj)) / NTOT
//   P_bj = sum_vox z_j*(a_j - lse),  Q_bj = sum_vox (a_j - lse),
//   R0   = sum_vox (t==0)*(a_0 - lse),  s_bj = 1/(mx_bj + eps - mn_bj)
// None of P/Q/R0 depend on mn/mx -> ONE pass over all inputs.
struct Ws {
    unsigned int mn[6];   // float bits, idx b*3+(j-1); z>=0 so uint order == float order
    unsigned int mx[6];
    unsigned int pad[4];  // doubles 8B-aligned at offset 64
    double P[6];
    double Q[6];
    double R0[2];
};

__global__ void k_init(Ws* ws) {
    const int t = threadIdx.x;
    if (t < 6) {
        ws->mn[t] = INF_BITS;  // +inf
        ws->mx[t] = 0u;        // valid: z >= 0 always
        ws->P[t] = 0.0;
        ws->Q[t] = 0.0;
    }
    if (t < 2) ws->R0[t] = 0.0;
}

// Single full-data pass: per-(b,j) min/max of z AND the loss aggregates.
__global__ void k_fused(const float* __restrict__ x,
                        const int* __restrict__ tgt,
                        const float* __restrict__ dist,
                        Ws* __restrict__ ws) {
    const int half = gridDim.x >> 1;          // blocks per batch
    const int b = (blockIdx.x >= half) ? 1 : 0;
    const int bid = blockIdx.x - b * half;
    const int stride = half * blockDim.x;

    const int4* t4 = (const int4*)tgt + (size_t)b * NSQ;
    const float4* d4 = (const float4*)dist + (size_t)b * NSQ;
    const float4* xb = (const float4*)x + (size_t)b * NC * NSQ;

    float mn1 = __uint_as_float(INF_BITS), mn2 = mn1, mn3 = mn1;
    float mx1 = 0.f, mx2 = 0.f, mx3 = 0.f;
    float P1 = 0.f, P2 = 0.f, P3 = 0.f;
    float Q1 = 0.f, Q2 = 0.f, Q3 = 0.f;
    float R0 = 0.f;

    for (int q = bid * blockDim.x + threadIdx.x; q < NSQ; q += stride) {
        float4 x0 = xb[q];
        float4 x1 = xb[q + NSQ];
        float4 x2 = xb[q + 2 * NSQ];
        float4 x3 = xb[q + 3 * NSQ];
        int4 t = t4[q];
        float4 d = d4[q];
        int tk[4] = {t.x, t.y, t.z, t.w};
        float dk[4] = {d.x, d.y, d.z, d.w};
#pragma unroll
        for (int k = 0; k < 4; k++) {
            float a0 = ((const float*)&x0)[k];
            float a1 = ((const float*)&x1)[k];
            float a2 = ((const float*)&x2)[k];
            float a3 = ((const float*)&x3)[k];
            float m = fmaxf(fmaxf(a0, a1), fmaxf(a2, a3));
            float e = __expf(a0 - m) + __expf(a1 - m) + __expf(a2 - m) + __expf(a3 - m);
            float lse = m + __logf(e);
            int tt = tk[k];
            float z1 = (tt == 1) ? dk[k] : 0.f;
            float z2 = (tt == 2) ? dk[k] : 0.f;
            float z3 = (tt == 3) ? dk[k] : 0.f;
            mn1 = fminf(mn1, z1); mx1 = fmaxf(mx1, z1);
            mn2 = fminf(mn2, z2); mx2 = fmaxf(mx2, z2);
            mn3 = fminf(mn3, z3); mx3 = fmaxf(mx3, z3);
            float l1 = a1 - lse, l2 = a2 - lse, l3 = a3 - lse;
            P1 += z1 * l1; P2 += z2 * l2; P3 += z3 * l3;
            Q1 += l1; Q2 += l2; Q3 += l3;
            R0 += (tt == 0) ? (a0 - lse) : 0.f;
        }
    }

    // wave(64) butterfly over all 13 accumulators
    for (int off = 32; off; off >>= 1) {
        mn1 = fminf(mn1, __shfl_down(mn1, off, 64));
        mn2 = fminf(mn2, __shfl_down(mn2, off, 64));
        mn3 = fminf(mn3, __shfl_down(mn3, off, 64));
        mx1 = fmaxf(mx1, __shfl_down(mx1, off, 64));
        mx2 = fmaxf(mx2, __shfl_down(mx2, off, 64));
        mx3 = fmaxf(mx3, __shfl_down(mx3, off, 64));
        P1 += __shfl_down(P1, off, 64);
        P2 += __shfl_down(P2, off, 64);
        P3 += __shfl_down(P3, off, 64);
        Q1 += __shfl_down(Q1, off, 64);
        Q2 += __shfl_down(Q2, off, 64);
        Q3 += __shfl_down(Q3, off, 64);
        R0 += __shfl_down(R0, off, 64);
    }

    __shared__ float sv[4][13];
    const int wid = threadIdx.x >> 6;
    if ((threadIdx.x & 63) == 0) {
        sv[wid][0] = mn1; sv[wid][1] = mn2; sv[wid][2] = mn3;
        sv[wid][3] = mx1; sv[wid][4] = mx2; sv[wid][5] = mx3;
        sv[wid][6] = P1;  sv[wid][7] = P2;  sv[wid][8] = P3;
        sv[wid][9] = Q1;  sv[wid][10] = Q2; sv[wid][11] = Q3;
        sv[wid][12] = R0;
    }
    __syncthreads();
    const int i = threadIdx.x;  // one quantity per thread, 13 threads active
    if (i < 13) {
        float v = sv[0][i];
        if (i < 3)      { v = fminf(fminf(v, sv[1][i]), fminf(sv[2][i], sv[3][i])); }
        else if (i < 6) { v = fmaxf(fmaxf(v, sv[1][i]), fmaxf(sv[2][i], sv[3][i])); }
        else            { v = v + sv[1][i] + sv[2][i] + sv[3][i]; }
        if (i < 3)       atomicMin(&ws->mn[b * 3 + i], __float_as_uint(v));
        else if (i < 6)  atomicMax(&ws->mx[b * 3 + (i - 3)], __float_as_uint(v));
        else if (i < 9)  atomicAdd(&ws->P[b * 3 + (i - 6)], (double)v);
        else if (i < 12) atomicAdd(&ws->Q[b * 3 + (i - 9)], (double)v);
        else             atomicAdd(&ws->R0[b], (double)v);
    }
}

__global__ void k_final(const Ws* __restrict__ ws, float* __restrict__ out) {
    if (threadIdx.x == 0 && blockIdx.x == 0) {
        double acc = ws->R0[0] + ws->R0[1];
#pragma unroll
        for (int i = 0; i < 6; i++) {
            float mnf = __uint_as_float(ws->mn[i]);
            float mxf = __uint_as_float(ws->mx[i]);
            float sf = 1.0f / (mxf + EPSF - mnf);   // mirror reference fp32 scale
            acc += (double)sf * (ws->P[i] - (double)mnf * ws->Q[i]);
        }
        out[0] = (float)(-acc / (double)NTOT);
    }
}

extern "C" void kernel_launch(void* const* d_in, const int* in_sizes, int n_in,
                              void* d_out, int out_size, void* d_ws, size_t ws_size,
                              hipStream_t stream) {
    const float* net = (const float*)d_in[0];   // [B, C, D, H, W] fp32
    const int* tgt = (const int*)d_in[1];       // [B, 1, D, H, W] int
    const float* dist = (const float*)d_in[2];  // [B, D, H, W] fp32
    Ws* ws = (Ws*)d_ws;

    k_init<<<1, 64, 0, stream>>>(ws);
    // 1152 blocks/batch x 256 thr -> exactly 4 grid-stride iters over NSQ quads
    k_fused<<<2304, 256, 0, stream>>>(net, tgt, dist, ws);
    k_final<<<1, 64, 0, stream>>>(ws, (float*)d_out);
}